// Round 1
// baseline (1013.421 us; speedup 1.0000x reference)
//
#include <hip/hip_runtime.h>
#include <hip/hip_bf16.h>

#define HDIM 1024
#define VOCAB 32000
#define TTOK 2048
#define BETAF 0.1f
#define NPAIRS 4

#define BM 128
#define BN 128
#define BK 64
#define MT (TTOK/BM)   // 16
#define NT (VOCAB/BN)  // 250
#define KSTEPS (HDIM/BK) // 16

typedef __attribute__((ext_vector_type(4))) float f32x4;
typedef __attribute__((ext_vector_type(8))) short bf16x8;

__device__ __forceinline__ short f2bf(float f) {
    union { float f; unsigned u; } v; v.f = f;
    return (short)((v.u + 0x7FFFu + ((v.u >> 16) & 1u)) >> 16);  // RNE
}

// Computes logits tile [BM tokens x BN vocab] = X @ W^T + bias, then writes
// per-token partial sum of exp(logit) for this vocab tile.
// partial layout: [2 models][NT][TTOK]
__global__ __launch_bounds__(256) void gemm_expsum_kernel(
    const float* __restrict__ X0, const float* __restrict__ W0, const float* __restrict__ B0,
    const float* __restrict__ X1, const float* __restrict__ W1, const float* __restrict__ B1,
    float* __restrict__ partial)
{
    const int model = blockIdx.z;
    const float* __restrict__ X = model ? X1 : X0;
    const float* __restrict__ W = model ? W1 : W0;
    const float* __restrict__ Bi = model ? B1 : B0;
    const int tm = blockIdx.x;   // token tile 0..15
    const int tn = blockIdx.y;   // vocab tile 0..249

    __shared__ short As[BM*BK];      // 16 KB, K-major, XOR-swizzled
    __shared__ short Bs[BN*BK];      // 16 KB
    __shared__ float red[2][BM];     // cross-wave row-sum exchange

    const int tid  = threadIdx.x;
    const int lane = tid & 63;
    const int w    = tid >> 6;
    const int wr   = w >> 1, wc = w & 1;   // 2x2 wave grid, 64x64 per wave
    const int l16  = lane & 15, lhi = lane >> 4;

    f32x4 acc[4][4];
    #pragma unroll
    for (int m = 0; m < 4; ++m)
        #pragma unroll
        for (int n = 0; n < 4; ++n)
            acc[m][n] = (f32x4)0.f;

    for (int ks = 0; ks < KSTEPS; ++ks) {
        __syncthreads();   // previous iteration's ds_reads complete
        const int kbase = ks * BK;
        // stage A: 128x64 bf16; 1024 segs of 8 bf16; 4 per thread
        #pragma unroll
        for (int it = 0; it < 4; ++it) {
            int s = tid + it * 256;
            int row = s >> 3, kseg = s & 7;
            const float* g = X + (size_t)(tm*BM + row)*HDIM + kbase + kseg*8;
            f32x4 v0 = *(const f32x4*)g;
            f32x4 v1 = *(const f32x4*)(g + 4);
            bf16x8 b;
            b[0]=f2bf(v0[0]); b[1]=f2bf(v0[1]); b[2]=f2bf(v0[2]); b[3]=f2bf(v0[3]);
            b[4]=f2bf(v1[0]); b[5]=f2bf(v1[1]); b[6]=f2bf(v1[2]); b[7]=f2bf(v1[3]);
            int byte = (row*128 + kseg*16) ^ ((row & 7) << 4);
            *(bf16x8*)((char*)As + byte) = b;
        }
        // stage B (weights): same shape
        #pragma unroll
        for (int it = 0; it < 4; ++it) {
            int s = tid + it * 256;
            int row = s >> 3, kseg = s & 7;
            const float* g = W + (size_t)(tn*BN + row)*HDIM + kbase + kseg*8;
            f32x4 v0 = *(const f32x4*)g;
            f32x4 v1 = *(const f32x4*)(g + 4);
            bf16x8 b;
            b[0]=f2bf(v0[0]); b[1]=f2bf(v0[1]); b[2]=f2bf(v0[2]); b[3]=f2bf(v0[3]);
            b[4]=f2bf(v1[0]); b[5]=f2bf(v1[1]); b[6]=f2bf(v1[2]); b[7]=f2bf(v1[3]);
            int byte = (row*128 + kseg*16) ^ ((row & 7) << 4);
            *(bf16x8*)((char*)Bs + byte) = b;
        }
        __syncthreads();

        bf16x8 af[2][4], bfr[2][4];
        #pragma unroll
        for (int kk = 0; kk < 2; ++kk) {
            #pragma unroll
            for (int m = 0; m < 4; ++m) {
                int row = wr*64 + m*16 + l16;
                int byte = (row*128 + kk*64 + lhi*16) ^ ((row & 7) << 4);
                af[kk][m] = *(const bf16x8*)((const char*)As + byte);
            }
            #pragma unroll
            for (int n = 0; n < 4; ++n) {
                int row = wc*64 + n*16 + l16;
                int byte = (row*128 + kk*64 + lhi*16) ^ ((row & 7) << 4);
                bfr[kk][n] = *(const bf16x8*)((const char*)Bs + byte);
            }
        }
        #pragma unroll
        for (int kk = 0; kk < 2; ++kk)
            #pragma unroll
            for (int m = 0; m < 4; ++m)
                #pragma unroll
                for (int n = 0; n < 4; ++n)
                    acc[m][n] = __builtin_amdgcn_mfma_f32_16x16x32_bf16(
                        af[kk][m], bfr[kk][n], acc[m][n], 0, 0, 0);
    }

    // Epilogue: per-token sum of exp(logit + bias) over this block's 128 cols.
    // C/D layout (16x16x32): col = lane&15, row = (lane>>4)*4 + j
    float bv[4];
    #pragma unroll
    for (int n = 0; n < 4; ++n)
        bv[n] = Bi[tn*BN + wc*64 + n*16 + l16];

    #pragma unroll
    for (int m = 0; m < 4; ++m) {
        float rp[4];
        #pragma unroll
        for (int j = 0; j < 4; ++j) {
            float s = 0.f;
            #pragma unroll
            for (int n = 0; n < 4; ++n)
                s += __expf(acc[m][n][j] + bv[n]);
            rp[j] = s;
        }
        #pragma unroll
        for (int j = 0; j < 4; ++j) {
            float s = rp[j];
            s += __shfl_xor(s, 1);
            s += __shfl_xor(s, 2);
            s += __shfl_xor(s, 4);
            s += __shfl_xor(s, 8);
            if (l16 == 0)
                red[wc][wr*64 + m*16 + lhi*4 + j] = s;
        }
    }
    __syncthreads();
    if (tid < BM) {
        float s = red[0][tid] + red[1][tid];
        partial[((size_t)model*NT + tn)*TTOK + tm*BM + tid] = s;
    }
}

// Target logits in exact fp32: tgt[model][t] = dot(X[t], W[target[t]]) + bias[target[t]]
__global__ __launch_bounds__(256) void tgt_kernel(
    const float* __restrict__ X0, const float* __restrict__ W0, const float* __restrict__ B0,
    const float* __restrict__ X1, const float* __restrict__ W1, const float* __restrict__ B1,
    const int* __restrict__ target, float* __restrict__ tgt)
{
    int gw = blockIdx.x * 4 + (threadIdx.x >> 6);  // 0..4095 wave tasks
    int lane = threadIdx.x & 63;
    int model = gw >> 11;
    int t = gw & (TTOK - 1);
    const float* X = model ? X1 : X0;
    const float* W = model ? W1 : W0;
    const float* Bi = model ? B1 : B0;
    int tg = target[t];
    int stg = tg < 0 ? 0 : (tg >= VOCAB ? VOCAB - 1 : tg);
    const float* xr = X + (size_t)t * HDIM;
    const float* wrow = W + (size_t)stg * HDIM;
    float s = 0.f;
    #pragma unroll
    for (int i = 0; i < 4; ++i) {
        int k = i * 256 + lane * 4;
        f32x4 xv = *(const f32x4*)(xr + k);
        f32x4 wv = *(const f32x4*)(wrow + k);
        s += xv[0]*wv[0] + xv[1]*wv[1] + xv[2]*wv[2] + xv[3]*wv[3];
    }
    s += __shfl_xor(s, 1);  s += __shfl_xor(s, 2);  s += __shfl_xor(s, 4);
    s += __shfl_xor(s, 8);  s += __shfl_xor(s, 16); s += __shfl_xor(s, 32);
    if (lane == 0)
        tgt[model * TTOK + t] = s + Bi[stg];
}

// Sum partials -> logZ; tok_logp = tgt - logZ; per-seq sums; DPO loss.
__global__ __launch_bounds__(512) void finalize_kernel(
    const float* __restrict__ partial, const float* __restrict__ tgt,
    const int* __restrict__ target, float* __restrict__ out)
{
    int tid = threadIdx.x;
    float acc = 0.f;
    #pragma unroll
    for (int i = 0; i < 8; ++i) {
        int g = tid * 8 + i;          // 0..4095 ; 8 consecutive tokens, same seq
        int model = g >> 11;
        int t = g & (TTOK - 1);
        const float* p = partial + (size_t)model * NT * TTOK + t;
        float S = 0.f;
        for (int j = 0; j < NT; ++j) S += p[(size_t)j * TTOK];
        float lp = tgt[g] - __logf(S);
        if (target[t] == -100) lp = 0.f;
        acc += lp;
    }
    // 32-thread groups = one (model, seq)
    acc += __shfl_xor(acc, 1);  acc += __shfl_xor(acc, 2);
    acc += __shfl_xor(acc, 4);  acc += __shfl_xor(acc, 8);
    acc += __shfl_xor(acc, 16);
    __shared__ float ps[16];
    if ((tid & 31) == 0) ps[tid >> 5] = acc;   // ps[0..7]=policy seq, ps[8..15]=ref seq
    __syncthreads();
    if (tid == 0) {
        float loss = 0.f;
        #pragma unroll
        for (int p = 0; p < NPAIRS; ++p) {
            float cho = ps[2*p]     - ps[8 + 2*p];
            float rej = ps[2*p + 1] - ps[8 + 2*p + 1];
            float z = BETAF * (cho - rej);
            float lsig = fminf(z, 0.f) - log1pf(__expf(-fabsf(z)));
            loss += -lsig;
        }
        out[0] = loss / (float)NPAIRS;
    }
}

extern "C" void kernel_launch(void* const* d_in, const int* in_sizes, int n_in,
                              void* d_out, int out_size, void* d_ws, size_t ws_size,
                              hipStream_t stream) {
    const float* x    = (const float*)d_in[0];
    const float* wgt  = (const float*)d_in[1];
    const float* bias = (const float*)d_in[2];
    const float* rx   = (const float*)d_in[3];
    const float* rwgt = (const float*)d_in[4];
    const float* rb   = (const float*)d_in[5];
    const int* target = (const int*)d_in[6];
    float* out = (float*)d_out;

    float* partial = (float*)d_ws;                       // 2*250*2048 floats = 4 MB
    float* tgtb    = partial + (size_t)2 * NT * TTOK;    // 4096 floats

    dim3 grid(MT, NT, 2);
    gemm_expsum_kernel<<<grid, 256, 0, stream>>>(x, wgt, bias, rx, rwgt, rb, partial);
    tgt_kernel<<<(2 * TTOK) / 4, 256, 0, stream>>>(x, wgt, bias, rx, rwgt, rb, target, tgtb);
    finalize_kernel<<<1, 512, 0, stream>>>(partial, tgtb, target, out);
}

// Round 2
// 556.228 us; speedup vs baseline: 1.8220x; 1.8220x over previous
//
#include <hip/hip_runtime.h>
#include <hip/hip_bf16.h>

#define HDIM 1024
#define VOCAB 32000
#define TTOK 2048
#define BETAF 0.1f
#define NPAIRS 4

#define BM 128
#define BN 128
#define BK 64
#define MT (TTOK/BM)     // 16
#define NT (VOCAB/BN)    // 250
#define KSTEPS (HDIM/BK) // 16

typedef __attribute__((ext_vector_type(4))) float f32x4;
typedef __attribute__((ext_vector_type(8))) short bf16x8;

__device__ __forceinline__ short f2bf(float f) {
    union { float f; unsigned u; } v; v.f = f;
    return (short)((v.u + 0x7FFFu + ((v.u >> 16) & 1u)) >> 16);  // RNE
}

__device__ __forceinline__ void gld_lds16(const void* g, void* l) {
    __builtin_amdgcn_global_load_lds(
        (const __attribute__((address_space(1))) unsigned int*)g,
        (__attribute__((address_space(3))) unsigned int*)l, 16, 0, 0);
}

// ---------------- fp32 -> bf16 pre-convert (grid-stride, 8 elems/thread) ----
__global__ __launch_bounds__(256) void convert_kernel(
    const float* __restrict__ src, short* __restrict__ dst, int n8)
{
    int stride = gridDim.x * blockDim.x;
    for (int i = blockIdx.x * blockDim.x + threadIdx.x; i < n8; i += stride) {
        size_t off = (size_t)i * 8;
        f32x4 v0 = *(const f32x4*)(src + off);
        f32x4 v1 = *(const f32x4*)(src + off + 4);
        bf16x8 b;
        b[0]=f2bf(v0[0]); b[1]=f2bf(v0[1]); b[2]=f2bf(v0[2]); b[3]=f2bf(v0[3]);
        b[4]=f2bf(v1[0]); b[5]=f2bf(v1[1]); b[6]=f2bf(v1[2]); b[7]=f2bf(v1[3]);
        *(bf16x8*)(dst + off) = b;
    }
}

// ---------------- main GEMM: bf16 inputs, global_load_lds staging ----------
// logits tile [BM tok x BN vocab] = X @ W^T (+bias in epilogue), writes
// per-token partial sum of exp(logit). partial: [2][NT][TTOK]
__global__ __launch_bounds__(256) void gemm_expsum_bf16(
    const short* __restrict__ Xb, const short* __restrict__ Wb,
    const float* __restrict__ B0, const float* __restrict__ B1,
    float* __restrict__ partial)
{
    const int model = blockIdx.z;
    const short* __restrict__ X = Xb + (size_t)model * TTOK * HDIM;
    const short* __restrict__ W = Wb + (size_t)model * VOCAB * HDIM;
    const float* __restrict__ Bi = model ? B1 : B0;
    const int tm = blockIdx.x;
    const int tn = blockIdx.y;

    __shared__ short As[BM*BK];   // 16 KB, row-major [128][64], linear (gld_lds)
    __shared__ short Bs[BN*BK];   // 16 KB
    __shared__ float red[2][BM];

    const int tid  = threadIdx.x;
    const int lane = tid & 63;
    const int w    = tid >> 6;
    const int wr   = w >> 1, wc = w & 1;    // 2x2 waves, 64x64 out each
    const int l16  = lane & 15, lhi = lane >> 4;

    f32x4 acc[4][4];
    #pragma unroll
    for (int m = 0; m < 4; ++m)
        #pragma unroll
        for (int n = 0; n < 4; ++n)
            acc[m][n] = (f32x4)0.f;

    const short* Abase = X + (size_t)tm * BM * HDIM;
    const short* Bbase = W + (size_t)tn * BN * HDIM;

    for (int ks = 0; ks < KSTEPS; ++ks) {
        const int kbase = ks * BK;
        // stage: 1024 chunks of 16B per tile; wave-uniform LDS dest + lane*16
        #pragma unroll
        for (int it = 0; it < 4; ++it) {
            int c = it * 256 + w * 64 + lane;   // chunk id, per-lane global src
            int row = c >> 3, kseg = c & 7;
            gld_lds16(Abase + (size_t)row * HDIM + kbase + kseg * 8,
                      (char*)As + (it * 256 + w * 64) * 16);
            gld_lds16(Bbase + (size_t)row * HDIM + kbase + kseg * 8,
                      (char*)Bs + (it * 256 + w * 64) * 16);
        }
        __syncthreads();   // drains vmcnt (gld_lds done) before frag reads

        bf16x8 af[2][4], bfr[2][4];
        #pragma unroll
        for (int kk = 0; kk < 2; ++kk) {
            #pragma unroll
            for (int m = 0; m < 4; ++m) {
                int row = wr*64 + m*16 + l16;
                af[kk][m] = *(const bf16x8*)((const char*)As + row*128 + kk*64 + lhi*16);
            }
            #pragma unroll
            for (int n = 0; n < 4; ++n) {
                int row = wc*64 + n*16 + l16;
                bfr[kk][n] = *(const bf16x8*)((const char*)Bs + row*128 + kk*64 + lhi*16);
            }
        }
        #pragma unroll
        for (int kk = 0; kk < 2; ++kk)
            #pragma unroll
            for (int m = 0; m < 4; ++m)
                #pragma unroll
                for (int n = 0; n < 4; ++n)
                    acc[m][n] = __builtin_amdgcn_mfma_f32_16x16x32_bf16(
                        af[kk][m], bfr[kk][n], acc[m][n], 0, 0, 0);
        __syncthreads();   // frag reads done before next stage overwrites
    }

    // Epilogue: per-token sum of exp(logit + bias) over 128 cols.
    // C/D: col = lane&15, row = (lane>>4)*4 + j
    float bv[4];
    #pragma unroll
    for (int n = 0; n < 4; ++n)
        bv[n] = Bi[tn*BN + wc*64 + n*16 + l16];

    #pragma unroll
    for (int m = 0; m < 4; ++m) {
        float rp[4];
        #pragma unroll
        for (int j = 0; j < 4; ++j) {
            float s = 0.f;
            #pragma unroll
            for (int n = 0; n < 4; ++n)
                s += __expf(acc[m][n][j] + bv[n]);
            rp[j] = s;
        }
        #pragma unroll
        for (int j = 0; j < 4; ++j) {
            float s = rp[j];
            s += __shfl_xor(s, 1);
            s += __shfl_xor(s, 2);
            s += __shfl_xor(s, 4);
            s += __shfl_xor(s, 8);
            if (l16 == 0)
                red[wc][wr*64 + m*16 + lhi*4 + j] = s;
        }
    }
    __syncthreads();
    if (tid < BM) {
        float s = red[0][tid] + red[1][tid];
        partial[((size_t)model*NT + tn)*TTOK + tm*BM + tid] = s;
    }
}

// ---------------- fallback GEMM (round-1, inline convert) ------------------
__global__ __launch_bounds__(256) void gemm_expsum_f32(
    const float* __restrict__ X0, const float* __restrict__ W0, const float* __restrict__ B0,
    const float* __restrict__ X1, const float* __restrict__ W1, const float* __restrict__ B1,
    float* __restrict__ partial)
{
    const int model = blockIdx.z;
    const float* __restrict__ X = model ? X1 : X0;
    const float* __restrict__ W = model ? W1 : W0;
    const float* __restrict__ Bi = model ? B1 : B0;
    const int tm = blockIdx.x;
    const int tn = blockIdx.y;

    __shared__ short As[BM*BK];
    __shared__ short Bs[BN*BK];
    __shared__ float red[2][BM];

    const int tid  = threadIdx.x;
    const int lane = tid & 63;
    const int w    = tid >> 6;
    const int wr   = w >> 1, wc = w & 1;
    const int l16  = lane & 15, lhi = lane >> 4;

    f32x4 acc[4][4];
    #pragma unroll
    for (int m = 0; m < 4; ++m)
        #pragma unroll
        for (int n = 0; n < 4; ++n)
            acc[m][n] = (f32x4)0.f;

    for (int ks = 0; ks < KSTEPS; ++ks) {
        __syncthreads();
        const int kbase = ks * BK;
        #pragma unroll
        for (int it = 0; it < 4; ++it) {
            int s = tid + it * 256;
            int row = s >> 3, kseg = s & 7;
            const float* g = X + (size_t)(tm*BM + row)*HDIM + kbase + kseg*8;
            f32x4 v0 = *(const f32x4*)g;
            f32x4 v1 = *(const f32x4*)(g + 4);
            bf16x8 b;
            b[0]=f2bf(v0[0]); b[1]=f2bf(v0[1]); b[2]=f2bf(v0[2]); b[3]=f2bf(v0[3]);
            b[4]=f2bf(v1[0]); b[5]=f2bf(v1[1]); b[6]=f2bf(v1[2]); b[7]=f2bf(v1[3]);
            int byte = (row*128 + kseg*16) ^ ((row & 7) << 4);
            *(bf16x8*)((char*)As + byte) = b;
        }
        #pragma unroll
        for (int it = 0; it < 4; ++it) {
            int s = tid + it * 256;
            int row = s >> 3, kseg = s & 7;
            const float* g = W + (size_t)(tn*BN + row)*HDIM + kbase + kseg*8;
            f32x4 v0 = *(const f32x4*)g;
            f32x4 v1 = *(const f32x4*)(g + 4);
            bf16x8 b;
            b[0]=f2bf(v0[0]); b[1]=f2bf(v0[1]); b[2]=f2bf(v0[2]); b[3]=f2bf(v0[3]);
            b[4]=f2bf(v1[0]); b[5]=f2bf(v1[1]); b[6]=f2bf(v1[2]); b[7]=f2bf(v1[3]);
            int byte = (row*128 + kseg*16) ^ ((row & 7) << 4);
            *(bf16x8*)((char*)Bs + byte) = b;
        }
        __syncthreads();

        bf16x8 af[2][4], bfr[2][4];
        #pragma unroll
        for (int kk = 0; kk < 2; ++kk) {
            #pragma unroll
            for (int m = 0; m < 4; ++m) {
                int row = wr*64 + m*16 + l16;
                int byte = (row*128 + kk*64 + lhi*16) ^ ((row & 7) << 4);
                af[kk][m] = *(const bf16x8*)((const char*)As + byte);
            }
            #pragma unroll
            for (int n = 0; n < 4; ++n) {
                int row = wc*64 + n*16 + l16;
                int byte = (row*128 + kk*64 + lhi*16) ^ ((row & 7) << 4);
                bfr[kk][n] = *(const bf16x8*)((const char*)Bs + byte);
            }
        }
        #pragma unroll
        for (int kk = 0; kk < 2; ++kk)
            #pragma unroll
            for (int m = 0; m < 4; ++m)
                #pragma unroll
                for (int n = 0; n < 4; ++n)
                    acc[m][n] = __builtin_amdgcn_mfma_f32_16x16x32_bf16(
                        af[kk][m], bfr[kk][n], acc[m][n], 0, 0, 0);
    }

    float bv[4];
    #pragma unroll
    for (int n = 0; n < 4; ++n)
        bv[n] = Bi[tn*BN + wc*64 + n*16 + l16];

    #pragma unroll
    for (int m = 0; m < 4; ++m) {
        float rp[4];
        #pragma unroll
        for (int j = 0; j < 4; ++j) {
            float s = 0.f;
            #pragma unroll
            for (int n = 0; n < 4; ++n)
                s += __expf(acc[m][n][j] + bv[n]);
            rp[j] = s;
        }
        #pragma unroll
        for (int j = 0; j < 4; ++j) {
            float s = rp[j];
            s += __shfl_xor(s, 1);
            s += __shfl_xor(s, 2);
            s += __shfl_xor(s, 4);
            s += __shfl_xor(s, 8);
            if (l16 == 0)
                red[wc][wr*64 + m*16 + lhi*4 + j] = s;
        }
    }
    __syncthreads();
    if (tid < BM) {
        float s = red[0][tid] + red[1][tid];
        partial[((size_t)model*NT + tn)*TTOK + tm*BM + tid] = s;
    }
}

// ---------------- exact fp32 target logits ---------------------------------
__global__ __launch_bounds__(256) void tgt_kernel(
    const float* __restrict__ X0, const float* __restrict__ W0, const float* __restrict__ B0,
    const float* __restrict__ X1, const float* __restrict__ W1, const float* __restrict__ B1,
    const int* __restrict__ target, float* __restrict__ tgt)
{
    int gw = blockIdx.x * 4 + (threadIdx.x >> 6);
    int lane = threadIdx.x & 63;
    int model = gw >> 11;
    int t = gw & (TTOK - 1);
    const float* X = model ? X1 : X0;
    const float* W = model ? W1 : W0;
    const float* Bi = model ? B1 : B0;
    int tg = target[t];
    int stg = tg < 0 ? 0 : (tg >= VOCAB ? VOCAB - 1 : tg);
    const float* xr = X + (size_t)t * HDIM;
    const float* wrow = W + (size_t)stg * HDIM;
    float s = 0.f;
    #pragma unroll
    for (int i = 0; i < 4; ++i) {
        int k = i * 256 + lane * 4;
        f32x4 xv = *(const f32x4*)(xr + k);
        f32x4 wv = *(const f32x4*)(wrow + k);
        s += xv[0]*wv[0] + xv[1]*wv[1] + xv[2]*wv[2] + xv[3]*wv[3];
    }
    s += __shfl_xor(s, 1);  s += __shfl_xor(s, 2);  s += __shfl_xor(s, 4);
    s += __shfl_xor(s, 8);  s += __shfl_xor(s, 16); s += __shfl_xor(s, 32);
    if (lane == 0)
        tgt[model * TTOK + t] = s + Bi[stg];
}

// ---------------- coalesced logZ reduction ---------------------------------
// thread g = (model, token); reads across vocab tiles are contiguous per wave
__global__ __launch_bounds__(256) void logz_kernel(
    const float* __restrict__ partial, const float* __restrict__ tgt,
    const int* __restrict__ target, float* __restrict__ tok_lp)
{
    int g = blockIdx.x * 256 + threadIdx.x;   // 0..4095
    int m = g >> 11;
    int t = g & (TTOK - 1);
    const float* p = partial + (size_t)m * NT * TTOK + t;
    float S = 0.f;
    #pragma unroll 2
    for (int j = 0; j < NT; ++j) S += p[(size_t)j * TTOK];
    float lp = tgt[g] - __logf(S);
    if (target[t] == -100) lp = 0.f;
    tok_lp[g] = lp;
}

// ---------------- per-seq sums + DPO loss ----------------------------------
__global__ __launch_bounds__(512) void loss_kernel(
    const float* __restrict__ tok_lp, float* __restrict__ out)
{
    int tid = threadIdx.x;
    float acc = 0.f;
    #pragma unroll
    for (int i = 0; i < 8; ++i)
        acc += tok_lp[tid * 8 + i];
    acc += __shfl_xor(acc, 1);  acc += __shfl_xor(acc, 2);
    acc += __shfl_xor(acc, 4);  acc += __shfl_xor(acc, 8);
    acc += __shfl_xor(acc, 16);
    __shared__ float ps[16];
    if ((tid & 31) == 0) ps[tid >> 5] = acc;
    __syncthreads();
    if (tid == 0) {
        float loss = 0.f;
        #pragma unroll
        for (int p = 0; p < NPAIRS; ++p) {
            float cho = ps[2*p]     - ps[8 + 2*p];
            float rej = ps[2*p + 1] - ps[8 + 2*p + 1];
            float z = BETAF * (cho - rej);
            float lsig = fminf(z, 0.f) - log1pf(__expf(-fabsf(z)));
            loss += -lsig;
        }
        out[0] = loss / (float)NPAIRS;
    }
}

// fallback finalize (round-1): single block, strided partial reads
__global__ __launch_bounds__(512) void finalize_kernel(
    const float* __restrict__ partial, const float* __restrict__ tgt,
    const int* __restrict__ target, float* __restrict__ out)
{
    int tid = threadIdx.x;
    float acc = 0.f;
    #pragma unroll
    for (int i = 0; i < 8; ++i) {
        int g = tid * 8 + i;
        int model = g >> 11;
        int t = g & (TTOK - 1);
        const float* p = partial + (size_t)model * NT * TTOK + t;
        float S = 0.f;
        for (int j = 0; j < NT; ++j) S += p[(size_t)j * TTOK];
        float lp = tgt[g] - __logf(S);
        if (target[t] == -100) lp = 0.f;
        acc += lp;
    }
    acc += __shfl_xor(acc, 1);  acc += __shfl_xor(acc, 2);
    acc += __shfl_xor(acc, 4);  acc += __shfl_xor(acc, 8);
    acc += __shfl_xor(acc, 16);
    __shared__ float ps[16];
    if ((tid & 31) == 0) ps[tid >> 5] = acc;
    __syncthreads();
    if (tid == 0) {
        float loss = 0.f;
        #pragma unroll
        for (int p = 0; p < NPAIRS; ++p) {
            float cho = ps[2*p]     - ps[8 + 2*p];
            float rej = ps[2*p + 1] - ps[8 + 2*p + 1];
            float z = BETAF * (cho - rej);
            float lsig = fminf(z, 0.f) - log1pf(__expf(-fabsf(z)));
            loss += -lsig;
        }
        out[0] = loss / (float)NPAIRS;
    }
}

extern "C" void kernel_launch(void* const* d_in, const int* in_sizes, int n_in,
                              void* d_out, int out_size, void* d_ws, size_t ws_size,
                              hipStream_t stream) {
    const float* x    = (const float*)d_in[0];
    const float* wgt  = (const float*)d_in[1];
    const float* bias = (const float*)d_in[2];
    const float* rx   = (const float*)d_in[3];
    const float* rwgt = (const float*)d_in[4];
    const float* rb   = (const float*)d_in[5];
    const int* target = (const int*)d_in[6];
    float* out = (float*)d_out;

    // ws layout
    float* partial = (float*)d_ws;                       // 2*250*2048 f = 4 MB
    float* tgtb    = partial + (size_t)2 * NT * TTOK;    // 4096 f
    float* tok_lp  = tgtb + 2 * TTOK;                    // 4096 f
    short* Xb      = (short*)(tok_lp + 2 * TTOK);        // 2*2048*1024 bf16 = 8 MB
    short* Wb      = Xb + (size_t)2 * TTOK * HDIM;       // 2*32000*1024 bf16 = 131 MB
    size_t need = (size_t)((char*)(Wb + (size_t)2 * VOCAB * HDIM) - (char*)d_ws);

    dim3 grid(MT, NT, 2);
    if (ws_size >= need) {
        int xn8 = TTOK * HDIM / 8;          // 262144
        int wn8 = VOCAB * HDIM / 8;         // 4096000
        convert_kernel<<<1024, 256, 0, stream>>>(x,    Xb,                       xn8);
        convert_kernel<<<1024, 256, 0, stream>>>(rx,   Xb + (size_t)TTOK*HDIM,   xn8);
        convert_kernel<<<2048, 256, 0, stream>>>(wgt,  Wb,                       wn8);
        convert_kernel<<<2048, 256, 0, stream>>>(rwgt, Wb + (size_t)VOCAB*HDIM,  wn8);
        gemm_expsum_bf16<<<grid, 256, 0, stream>>>(Xb, Wb, bias, rb, partial);
        tgt_kernel<<<(2 * TTOK) / 4, 256, 0, stream>>>(x, wgt, bias, rx, rwgt, rb, target, tgtb);
        logz_kernel<<<16, 256, 0, stream>>>(partial, tgtb, target, tok_lp);
        loss_kernel<<<1, 512, 0, stream>>>(tok_lp, out);
    } else {
        gemm_expsum_f32<<<grid, 256, 0, stream>>>(x, wgt, bias, rx, rwgt, rb, partial);
        tgt_kernel<<<(2 * TTOK) / 4, 256, 0, stream>>>(x, wgt, bias, rx, rwgt, rb, target, tgtb);
        finalize_kernel<<<1, 512, 0, stream>>>(partial, tgtb, target, out);
    }
}

// Round 3
// 397.172 us; speedup vs baseline: 2.5516x; 1.4005x over previous
//
#include <hip/hip_runtime.h>
#include <hip/hip_bf16.h>

#define HDIM 1024
#define VOCAB 32000
#define TTOK 2048
#define BETAF 0.1f
#define NPAIRS 4

#define BM 128
#define BN 128
#define BK 64
#define MT (TTOK/BM)     // 16
#define NT (VOCAB/BN)    // 250
#define KSTEPS (HDIM/BK) // 16
#define NWG (MT*NT*2)    // 8000, %8==0

typedef __attribute__((ext_vector_type(4))) float f32x4;
typedef __attribute__((ext_vector_type(8))) short bf16x8;

__device__ __forceinline__ short f2bf(float f) {
    union { float f; unsigned u; } v; v.f = f;
    return (short)((v.u + 0x7FFFu + ((v.u >> 16) & 1u)) >> 16);  // RNE
}

__device__ __forceinline__ void gld_lds16(const void* g, void* l) {
    __builtin_amdgcn_global_load_lds(
        (const __attribute__((address_space(1))) unsigned int*)g,
        (__attribute__((address_space(3))) unsigned int*)l, 16, 0, 0);
}

// ---------------- fp32 -> bf16 pre-convert (grid-stride, 8 elems/thread) ----
__global__ __launch_bounds__(256) void convert_kernel(
    const float* __restrict__ src, short* __restrict__ dst, int n8)
{
    int stride = gridDim.x * blockDim.x;
    for (int i = blockIdx.x * blockDim.x + threadIdx.x; i < n8; i += stride) {
        size_t off = (size_t)i * 8;
        f32x4 v0 = *(const f32x4*)(src + off);
        f32x4 v1 = *(const f32x4*)(src + off + 4);
        bf16x8 b;
        b[0]=f2bf(v0[0]); b[1]=f2bf(v0[1]); b[2]=f2bf(v0[2]); b[3]=f2bf(v0[3]);
        b[4]=f2bf(v1[0]); b[5]=f2bf(v1[1]); b[6]=f2bf(v1[2]); b[7]=f2bf(v1[3]);
        *(bf16x8*)(dst + off) = b;
    }
}

// ---------------- main GEMM: bf16 in, gld_lds staging, swizzled LDS --------
// Layout invariant (rule #21): LDS dest linear (gld_lds writes base+lane*16);
// global source pre-swizzled kseg^=(row&7); reads XOR the same involution.
// Resulting layout == round-1's verified explicit-swizzle layout (0 conflicts).
__global__ __launch_bounds__(256, 4) void gemm_expsum_bf16(
    const short* __restrict__ Xb, const short* __restrict__ Wb,
    const float* __restrict__ B0, const float* __restrict__ B1,
    float* __restrict__ partial)
{
    // T1: bijective XCD swizzle (NWG % 8 == 0), tm fastest for W-panel reuse
    int raw = blockIdx.x;
    int swz = (raw & 7) * (NWG / 8) + (raw >> 3);
    const int model = swz / (MT * NT);
    int rem = swz % (MT * NT);
    const int tn = rem / MT;
    const int tm = rem % MT;

    const short* __restrict__ X = Xb + (size_t)model * TTOK * HDIM;
    const short* __restrict__ W = Wb + (size_t)model * VOCAB * HDIM;
    const float* __restrict__ Bi = model ? B1 : B0;

    __shared__ short As[BM*BK];   // 16 KB
    __shared__ short Bs[BN*BK];   // 16 KB
    __shared__ float red[2][BM];

    const int tid  = threadIdx.x;
    const int lane = tid & 63;
    const int w    = tid >> 6;
    const int wr   = w >> 1, wc = w & 1;    // 2x2 waves, 64x64 out each
    const int l16  = lane & 15, lhi = lane >> 4;

    f32x4 acc[4][4];
    #pragma unroll
    for (int m = 0; m < 4; ++m)
        #pragma unroll
        for (int n = 0; n < 4; ++n)
            acc[m][n] = (f32x4)0.f;

    const short* Abase = X + (size_t)tm * BM * HDIM;
    const short* Bbase = W + (size_t)tn * BN * HDIM;

    for (int ks = 0; ks < KSTEPS; ++ks) {
        const int kbase = ks * BK;
        // stage: 1024 x 16B chunks per tile. Linear LDS slot c holds global
        // chunk (row = c>>3, kseg = (c&7) ^ (row&7)).
        #pragma unroll
        for (int it = 0; it < 4; ++it) {
            int c = it * 256 + w * 64 + lane;
            int row = c >> 3;
            int ksg = (c & 7) ^ (row & 7);      // pre-swizzled source
            gld_lds16(Abase + (size_t)row * HDIM + kbase + ksg * 8,
                      (char*)As + (it * 256 + w * 64) * 16);
            gld_lds16(Bbase + (size_t)row * HDIM + kbase + ksg * 8,
                      (char*)Bs + (it * 256 + w * 64) * 16);
        }
        __syncthreads();   // drains vmcnt (gld_lds) before frag reads

        bf16x8 af[2][4], bfr[2][4];
        #pragma unroll
        for (int kk = 0; kk < 2; ++kk) {
            #pragma unroll
            for (int m = 0; m < 4; ++m) {
                int row = wr*64 + m*16 + l16;
                int byte = (row*128 + kk*64 + lhi*16) ^ ((row & 7) << 4);
                af[kk][m] = *(const bf16x8*)((const char*)As + byte);
            }
            #pragma unroll
            for (int n = 0; n < 4; ++n) {
                int row = wc*64 + n*16 + l16;
                int byte = (row*128 + kk*64 + lhi*16) ^ ((row & 7) << 4);
                bfr[kk][n] = *(const bf16x8*)((const char*)Bs + byte);
            }
        }
        #pragma unroll
        for (int kk = 0; kk < 2; ++kk)
            #pragma unroll
            for (int m = 0; m < 4; ++m)
                #pragma unroll
                for (int n = 0; n < 4; ++n)
                    acc[m][n] = __builtin_amdgcn_mfma_f32_16x16x32_bf16(
                        af[kk][m], bfr[kk][n], acc[m][n], 0, 0, 0);
        __syncthreads();   // frag reads done before next stage overwrites
    }

    // Epilogue: per-token sum of exp(logit + bias) over 128 cols.
    // C/D: col = lane&15, row = (lane>>4)*4 + j
    float bv[4];
    #pragma unroll
    for (int n = 0; n < 4; ++n)
        bv[n] = Bi[tn*BN + wc*64 + n*16 + l16];

    #pragma unroll
    for (int m = 0; m < 4; ++m) {
        float rp[4];
        #pragma unroll
        for (int j = 0; j < 4; ++j) {
            float s = 0.f;
            #pragma unroll
            for (int n = 0; n < 4; ++n)
                s += __expf(acc[m][n][j] + bv[n]);
            rp[j] = s;
        }
        #pragma unroll
        for (int j = 0; j < 4; ++j) {
            float s = rp[j];
            s += __shfl_xor(s, 1);
            s += __shfl_xor(s, 2);
            s += __shfl_xor(s, 4);
            s += __shfl_xor(s, 8);
            if (l16 == 0)
                red[wc][wr*64 + m*16 + lhi*4 + j] = s;
        }
    }
    __syncthreads();
    if (tid < BM) {
        float s = red[0][tid] + red[1][tid];
        partial[((size_t)model*NT + tn)*TTOK + tm*BM + tid] = s;
    }
}

// ---------------- fallback GEMM (inline convert, explicit swizzle) ---------
__global__ __launch_bounds__(256) void gemm_expsum_f32(
    const float* __restrict__ X0, const float* __restrict__ W0, const float* __restrict__ B0,
    const float* __restrict__ X1, const float* __restrict__ W1, const float* __restrict__ B1,
    float* __restrict__ partial)
{
    const int model = blockIdx.z;
    const float* __restrict__ X = model ? X1 : X0;
    const float* __restrict__ W = model ? W1 : W0;
    const float* __restrict__ Bi = model ? B1 : B0;
    const int tm = blockIdx.x;
    const int tn = blockIdx.y;

    __shared__ short As[BM*BK];
    __shared__ short Bs[BN*BK];
    __shared__ float red[2][BM];

    const int tid  = threadIdx.x;
    const int lane = tid & 63;
    const int w    = tid >> 6;
    const int wr   = w >> 1, wc = w & 1;
    const int l16  = lane & 15, lhi = lane >> 4;

    f32x4 acc[4][4];
    #pragma unroll
    for (int m = 0; m < 4; ++m)
        #pragma unroll
        for (int n = 0; n < 4; ++n)
            acc[m][n] = (f32x4)0.f;

    for (int ks = 0; ks < KSTEPS; ++ks) {
        __syncthreads();
        const int kbase = ks * BK;
        #pragma unroll
        for (int it = 0; it < 4; ++it) {
            int s = tid + it * 256;
            int row = s >> 3, kseg = s & 7;
            const float* g = X + (size_t)(tm*BM + row)*HDIM + kbase + kseg*8;
            f32x4 v0 = *(const f32x4*)g;
            f32x4 v1 = *(const f32x4*)(g + 4);
            bf16x8 b;
            b[0]=f2bf(v0[0]); b[1]=f2bf(v0[1]); b[2]=f2bf(v0[2]); b[3]=f2bf(v0[3]);
            b[4]=f2bf(v1[0]); b[5]=f2bf(v1[1]); b[6]=f2bf(v1[2]); b[7]=f2bf(v1[3]);
            int byte = (row*128 + kseg*16) ^ ((row & 7) << 4);
            *(bf16x8*)((char*)As + byte) = b;
        }
        #pragma unroll
        for (int it = 0; it < 4; ++it) {
            int s = tid + it * 256;
            int row = s >> 3, kseg = s & 7;
            const float* g = W + (size_t)(tn*BN + row)*HDIM + kbase + kseg*8;
            f32x4 v0 = *(const f32x4*)g;
            f32x4 v1 = *(const f32x4*)(g + 4);
            bf16x8 b;
            b[0]=f2bf(v0[0]); b[1]=f2bf(v0[1]); b[2]=f2bf(v0[2]); b[3]=f2bf(v0[3]);
            b[4]=f2bf(v1[0]); b[5]=f2bf(v1[1]); b[6]=f2bf(v1[2]); b[7]=f2bf(v1[3]);
            int byte = (row*128 + kseg*16) ^ ((row & 7) << 4);
            *(bf16x8*)((char*)Bs + byte) = b;
        }
        __syncthreads();

        bf16x8 af[2][4], bfr[2][4];
        #pragma unroll
        for (int kk = 0; kk < 2; ++kk) {
            #pragma unroll
            for (int m = 0; m < 4; ++m) {
                int row = wr*64 + m*16 + l16;
                int byte = (row*128 + kk*64 + lhi*16) ^ ((row & 7) << 4);
                af[kk][m] = *(const bf16x8*)((const char*)As + byte);
            }
            #pragma unroll
            for (int n = 0; n < 4; ++n) {
                int row = wc*64 + n*16 + l16;
                int byte = (row*128 + kk*64 + lhi*16) ^ ((row & 7) << 4);
                bfr[kk][n] = *(const bf16x8*)((const char*)Bs + byte);
            }
        }
        #pragma unroll
        for (int kk = 0; kk < 2; ++kk)
            #pragma unroll
            for (int m = 0; m < 4; ++m)
                #pragma unroll
                for (int n = 0; n < 4; ++n)
                    acc[m][n] = __builtin_amdgcn_mfma_f32_16x16x32_bf16(
                        af[kk][m], bfr[kk][n], acc[m][n], 0, 0, 0);
    }

    float bv[4];
    #pragma unroll
    for (int n = 0; n < 4; ++n)
        bv[n] = Bi[tn*BN + wc*64 + n*16 + l16];

    #pragma unroll
    for (int m = 0; m < 4; ++m) {
        float rp[4];
        #pragma unroll
        for (int j = 0; j < 4; ++j) {
            float s = 0.f;
            #pragma unroll
            for (int n = 0; n < 4; ++n)
                s += __expf(acc[m][n][j] + bv[n]);
            rp[j] = s;
        }
        #pragma unroll
        for (int j = 0; j < 4; ++j) {
            float s = rp[j];
            s += __shfl_xor(s, 1);
            s += __shfl_xor(s, 2);
            s += __shfl_xor(s, 4);
            s += __shfl_xor(s, 8);
            if (l16 == 0)
                red[wc][wr*64 + m*16 + lhi*4 + j] = s;
        }
    }
    __syncthreads();
    if (tid < BM) {
        float s = red[0][tid] + red[1][tid];
        partial[((size_t)model*NT + tn)*TTOK + tm*BM + tid] = s;
    }
}

// ---------------- exact fp32 target logits ---------------------------------
__global__ __launch_bounds__(256) void tgt_kernel(
    const float* __restrict__ X0, const float* __restrict__ W0, const float* __restrict__ B0,
    const float* __restrict__ X1, const float* __restrict__ W1, const float* __restrict__ B1,
    const int* __restrict__ target, float* __restrict__ tgt)
{
    int gw = blockIdx.x * 4 + (threadIdx.x >> 6);
    int lane = threadIdx.x & 63;
    int model = gw >> 11;
    int t = gw & (TTOK - 1);
    const float* X = model ? X1 : X0;
    const float* W = model ? W1 : W0;
    const float* Bi = model ? B1 : B0;
    int tg = target[t];
    int stg = tg < 0 ? 0 : (tg >= VOCAB ? VOCAB - 1 : tg);
    const float* xr = X + (size_t)t * HDIM;
    const float* wrow = W + (size_t)stg * HDIM;
    float s = 0.f;
    #pragma unroll
    for (int i = 0; i < 4; ++i) {
        int k = i * 256 + lane * 4;
        f32x4 xv = *(const f32x4*)(xr + k);
        f32x4 wv = *(const f32x4*)(wrow + k);
        s += xv[0]*wv[0] + xv[1]*wv[1] + xv[2]*wv[2] + xv[3]*wv[3];
    }
    s += __shfl_xor(s, 1);  s += __shfl_xor(s, 2);  s += __shfl_xor(s, 4);
    s += __shfl_xor(s, 8);  s += __shfl_xor(s, 16); s += __shfl_xor(s, 32);
    if (lane == 0)
        tgt[model * TTOK + t] = s + Bi[stg];
}

// ---------------- coalesced logZ reduction ---------------------------------
__global__ __launch_bounds__(256) void logz_kernel(
    const float* __restrict__ partial, const float* __restrict__ tgt,
    const int* __restrict__ target, float* __restrict__ tok_lp)
{
    int g = blockIdx.x * 256 + threadIdx.x;   // 0..4095
    int m = g >> 11;
    int t = g & (TTOK - 1);
    const float* p = partial + (size_t)m * NT * TTOK + t;
    float S = 0.f;
    #pragma unroll 2
    for (int j = 0; j < NT; ++j) S += p[(size_t)j * TTOK];
    float lp = tgt[g] - __logf(S);
    if (target[t] == -100) lp = 0.f;
    tok_lp[g] = lp;
}

// ---------------- per-seq sums + DPO loss ----------------------------------
__global__ __launch_bounds__(512) void loss_kernel(
    const float* __restrict__ tok_lp, float* __restrict__ out)
{
    int tid = threadIdx.x;
    float acc = 0.f;
    #pragma unroll
    for (int i = 0; i < 8; ++i)
        acc += tok_lp[tid * 8 + i];
    acc += __shfl_xor(acc, 1);  acc += __shfl_xor(acc, 2);
    acc += __shfl_xor(acc, 4);  acc += __shfl_xor(acc, 8);
    acc += __shfl_xor(acc, 16);
    __shared__ float ps[16];
    if ((tid & 31) == 0) ps[tid >> 5] = acc;
    __syncthreads();
    if (tid == 0) {
        float loss = 0.f;
        #pragma unroll
        for (int p = 0; p < NPAIRS; ++p) {
            float cho = ps[2*p]     - ps[8 + 2*p];
            float rej = ps[2*p + 1] - ps[8 + 2*p + 1];
            float z = BETAF * (cho - rej);
            float lsig = fminf(z, 0.f) - log1pf(__expf(-fabsf(z)));
            loss += -lsig;
        }
        out[0] = loss / (float)NPAIRS;
    }
}

// fallback finalize: single block
__global__ __launch_bounds__(512) void finalize_kernel(
    const float* __restrict__ partial, const float* __restrict__ tgt,
    const int* __restrict__ target, float* __restrict__ out)
{
    int tid = threadIdx.x;
    float acc = 0.f;
    #pragma unroll
    for (int i = 0; i < 8; ++i) {
        int g = tid * 8 + i;
        int model = g >> 11;
        int t = g & (TTOK - 1);
        const float* p = partial + (size_t)model * NT * TTOK + t;
        float S = 0.f;
        for (int j = 0; j < NT; ++j) S += p[(size_t)j * TTOK];
        float lp = tgt[g] - __logf(S);
        if (target[t] == -100) lp = 0.f;
        acc += lp;
    }
    acc += __shfl_xor(acc, 1);  acc += __shfl_xor(acc, 2);
    acc += __shfl_xor(acc, 4);  acc += __shfl_xor(acc, 8);
    acc += __shfl_xor(acc, 16);
    __shared__ float ps[16];
    if ((tid & 31) == 0) ps[tid >> 5] = acc;
    __syncthreads();
    if (tid == 0) {
        float loss = 0.f;
        #pragma unroll
        for (int p = 0; p < NPAIRS; ++p) {
            float cho = ps[2*p]     - ps[8 + 2*p];
            float rej = ps[2*p + 1] - ps[8 + 2*p + 1];
            float z = BETAF * (cho - rej);
            float lsig = fminf(z, 0.f) - log1pf(__expf(-fabsf(z)));
            loss += -lsig;
        }
        out[0] = loss / (float)NPAIRS;
    }
}

extern "C" void kernel_launch(void* const* d_in, const int* in_sizes, int n_in,
                              void* d_out, int out_size, void* d_ws, size_t ws_size,
                              hipStream_t stream) {
    const float* x    = (const float*)d_in[0];
    const float* wgt  = (const float*)d_in[1];
    const float* bias = (const float*)d_in[2];
    const float* rx   = (const float*)d_in[3];
    const float* rwgt = (const float*)d_in[4];
    const float* rb   = (const float*)d_in[5];
    const int* target = (const int*)d_in[6];
    float* out = (float*)d_out;

    // ws layout
    float* partial = (float*)d_ws;                       // 2*250*2048 f = 4 MB
    float* tgtb    = partial + (size_t)2 * NT * TTOK;    // 4096 f
    float* tok_lp  = tgtb + 2 * TTOK;                    // 4096 f
    short* Xb      = (short*)(tok_lp + 2 * TTOK);        // 8 MB
    short* Wb      = Xb + (size_t)2 * TTOK * HDIM;       // 131 MB
    size_t need = (size_t)((char*)(Wb + (size_t)2 * VOCAB * HDIM) - (char*)d_ws);

    if (ws_size >= need) {
        int xn8 = TTOK * HDIM / 8;
        int wn8 = VOCAB * HDIM / 8;
        convert_kernel<<<1024, 256, 0, stream>>>(x,    Xb,                       xn8);
        convert_kernel<<<1024, 256, 0, stream>>>(rx,   Xb + (size_t)TTOK*HDIM,   xn8);
        convert_kernel<<<2048, 256, 0, stream>>>(wgt,  Wb,                       wn8);
        convert_kernel<<<2048, 256, 0, stream>>>(rwgt, Wb + (size_t)VOCAB*HDIM,  wn8);
        gemm_expsum_bf16<<<NWG, 256, 0, stream>>>(Xb, Wb, bias, rb, partial);
        tgt_kernel<<<(2 * TTOK) / 4, 256, 0, stream>>>(x, wgt, bias, rx, rwgt, rb, target, tgtb);
        logz_kernel<<<16, 256, 0, stream>>>(partial, tgtb, target, tok_lp);
        loss_kernel<<<1, 512, 0, stream>>>(tok_lp, out);
    } else {
        dim3 grid(MT, NT, 2);
        gemm_expsum_f32<<<grid, 256, 0, stream>>>(x, wgt, bias, rx, rwgt, rb, partial);
        tgt_kernel<<<(2 * TTOK) / 4, 256, 0, stream>>>(x, wgt, bias, rx, rwgt, rb, target, tgtb);
        finalize_kernel<<<1, 512, 0, stream>>>(partial, tgtb, target, out);
    }
}